// Round 5
// baseline (314.617 us; speedup 1.0000x reference)
//
#include <hip/hip_runtime.h>
#include <hip/hip_bf16.h>

#define ALPHA_ 1.0f
#define BETA_  0.5f
#define GAMMA_ 0.3f
#define EPS_   1e-8f

typedef unsigned short u16;
typedef unsigned int u32;

constexpr int B_ = 32, C_ = 256, F_ = 2048;
constexpr int NTOT = B_ * C_ * F_;          // 16777216
constexpr int NCC  = B_ * C_ * C_;          // 2097152
constexpr int NPOS = 10;                    // ti<=tj positions in 4x4 tile grid
constexpr int KSPL = 4;                     // K-split factor (K=2048 -> 4x512)
constexpr int NBLK = B_ * NPOS * KSPL;      // 1280 pci blocks (1280 % 8 == 0)
constexpr int NRED = B_ * NPOS * 64 * 64;   // 1310720 partial re/im elements

// symmetric tile positions: 4 diagonal first, then 6 strict-upper
__constant__ int TI_[NPOS] = {0, 1, 2, 3, 0, 0, 0, 1, 1, 2};
__constant__ int TJ_[NPOS] = {0, 1, 2, 3, 1, 2, 3, 2, 3, 3};

typedef __bf16 bf16x8 __attribute__((ext_vector_type(8)));
typedef float  f32x4  __attribute__((ext_vector_type(4)));

// round-to-nearest-even float -> bf16 bits (sin/cos inputs, no NaN/Inf)
__device__ __forceinline__ u32 f2bf(float x) {
    unsigned u = __float_as_uint(x);
    u += 0x7fffu + ((u >> 16) & 1u);
    return (u >> 16);
}

// ---------------------------------------------------------------------------
// Kernel A: elementwise mag/phase losses — CONTIGUOUS-COALESCED form.
// Rounds 0-4 all used ph[2g],ph[2g+1]: lane i -> base+32i, i.e. each
// dwordx4 wave-instruction spans 2KB at stride 32 with 50% density (32 line
// requests, 1KB useful; every line requested twice). That pattern capped all
// four structurally-different ew variants at 2.7-3.0 TB/s effective — half
// the 6.3 TB/s contiguous-float4 ceiling. Fix: ONE float4 per array per
// thread, g = tid: every wave-load is a contiguous aligned 1KB segment.
// 16384 blocks x 256 thr; 4 independent loads/thread; ~32 VGPR.
// Final reduction sharded over 64 partial slots (16384 blocks -> 256
// atomics/slot, spread in time).
// ---------------------------------------------------------------------------
__global__ void __launch_bounds__(256)
ew_kernel(const float4* __restrict__ mh, const float4* __restrict__ ph,
          const float4* __restrict__ mt, const float4* __restrict__ pt,
          float* __restrict__ part)
{
    __shared__ float sm[4], sp[4];
    const int g = blockIdx.x * 256 + threadIdx.x;   // 0..4194303 (float4 idx)
    float4 p = ph[g], q = pt[g], a = mh[g], b = mt[g];

    float msum = 0.f, psum = 0.f;
    float dm;
    dm = a.x - b.x; msum += dm * dm; psum += 1.f - __cosf(p.x - q.x);
    dm = a.y - b.y; msum += dm * dm; psum += 1.f - __cosf(p.y - q.y);
    dm = a.z - b.z; msum += dm * dm; psum += 1.f - __cosf(p.z - q.z);
    dm = a.w - b.w; msum += dm * dm; psum += 1.f - __cosf(p.w - q.w);

    #pragma unroll
    for (int o = 32; o > 0; o >>= 1) {
        msum += __shfl_down(msum, o, 64);
        psum += __shfl_down(psum, o, 64);
    }
    int lane = threadIdx.x & 63, wv = threadIdx.x >> 6;
    if (lane == 0) { sm[wv] = msum; sp[wv] = psum; }
    __syncthreads();
    if (threadIdx.x == 0) {
        int slot = blockIdx.x & 63;                 // 256 blocks per slot
        atomicAdd(&part[slot],      sm[0] + sm[1] + sm[2] + sm[3]);
        atomicAdd(&part[64 + slot], sp[0] + sp[1] + sp[2] + sp[3]);
    }
}

// ---------------------------------------------------------------------------
// Kernel B: batched MFMA partial re/im, SYMMETRIC tile set, K-split 4.
// (DELIBERATELY UNCHANGED: pci+coh account for ~195 us but have never been
// in the top-5. With ew shrunk, the dominant one surfaces next round with
// full counters — measure before editing.)
// ---------------------------------------------------------------------------
__device__ __forceinline__ void stage8(float4 a, float4 b, char* base, int pc) {
    float v[8] = {a.x, a.y, a.z, a.w, b.x, b.y, b.z, b.w};
    u32 cu[8], su[8];
    #pragma unroll
    for (int j = 0; j < 8; j++) {
        float s, c;
        __sincosf(v[j], &s, &c);
        cu[j] = f2bf(c);
        su[j] = f2bf(s);
    }
    *(int4*)(base + pc) = make_int4(
        (int)(cu[0] | (cu[1] << 16)), (int)(cu[2] | (cu[3] << 16)),
        (int)(cu[4] | (cu[5] << 16)), (int)(cu[6] | (cu[7] << 16)));
    *(int4*)(base + (pc ^ 128)) = make_int4(
        (int)(su[0] | (su[1] << 16)), (int)(su[2] | (su[3] << 16)),
        (int)(su[4] | (su[5] << 16)), (int)(su[6] | (su[7] << 16)));
}

__global__ void __launch_bounds__(256)
pci_kernel(const float* __restrict__ ph, float* __restrict__ slabs)
{
    __shared__ char lds[32768];          // A tile 16 KB | B tile 16 KB
    char* la = lds;
    char* lb = lds + 16384;

    // bijective XCD swizzle (NBLK % 8 == 0)
    const int bid = blockIdx.x;
    const int l   = (bid & 7) * (NBLK / 8) + (bid >> 3);
    const int h   = l & 3;                   // K-split index 0..3
    const int t4  = l >> 2;
    const int pos = t4 % NPOS;               // symmetric tile position
    const int y   = t4 / NPOS;               // batch
    const int i0 = TI_[pos] * 64, j0 = TJ_[pos] * 64;
    const bool diag = (i0 == j0);
    char* lbp = diag ? la : lb;              // diagonal: B-fragments from la

    const int t    = threadIdx.x;
    const int lane = t & 63, w = t >> 6;
    const int wrow = (w >> 1) * 32, wcol = (w & 1) * 32;
    const int m = lane & 15, q = lane >> 4;

    // staging: thread t covers (row0, oct) and (row1=row0+32, oct);
    // oct covers k = h*512 + it*64 + oct*8 .. +7
    const int row0 = t >> 3, oct = t & 7;
    const int row1 = row0 + 32;
    const float* gA0 = ph + ((size_t)(y * 256 + i0 + row0) * 2048 + h * 512 + oct * 8);
    const float* gA1 = ph + ((size_t)(y * 256 + i0 + row1) * 2048 + h * 512 + oct * 8);
    const float* gB0 = ph + ((size_t)(y * 256 + j0 + row0) * 2048 + h * 512 + oct * 8);
    const float* gB1 = ph + ((size_t)(y * 256 + j0 + row1) * 2048 + h * 512 + oct * 8);
    char* dA0 = la + row0 * 256;  const int pc0 = (oct ^ (row0 & 15)) * 16;
    char* dA1 = la + row1 * 256;  const int pc1 = (oct ^ (row1 & 15)) * 16;
    char* dB0 = lb + row0 * 256;
    char* dB1 = lb + row1 * 256;

    f32x4 zero = {0.f, 0.f, 0.f, 0.f};
    f32x4 accR[2][2], accSC[2][2], accCS[2][2];
    #pragma unroll
    for (int a = 0; a < 2; a++)
        #pragma unroll
        for (int c = 0; c < 2; c++) {
            accR[a][c] = zero; accSC[a][c] = zero; accCS[a][c] = zero;
        }

    for (int it = 0; it < 8; ++it) {         // 8 iters x BK=64 = K/4
        __syncthreads();                     // protect LDS from prior reads
        float4 a0 = *(const float4*)gA0, a1 = *(const float4*)(gA0 + 4);
        float4 a2 = *(const float4*)gA1, a3 = *(const float4*)(gA1 + 4);
        float4 b0, b1, b2, b3;
        if (!diag) {                         // block-uniform branch
            b0 = *(const float4*)gB0; b1 = *(const float4*)(gB0 + 4);
            b2 = *(const float4*)gB1; b3 = *(const float4*)(gB1 + 4);
        }
        gA0 += 64; gA1 += 64; gB0 += 64; gB1 += 64;
        stage8(a0, a1, dA0, pc0);
        stage8(a2, a3, dA1, pc1);
        if (!diag) {
            stage8(b0, b1, dB0, pc0);
            stage8(b2, b3, dB1, pc1);
        }
        __syncthreads();                     // ds_writes visible to all waves

        #pragma unroll
        for (int s = 0; s < 2; ++s) {
            bf16x8 fac[2], fas[2], fbc[2], fbs[2];
            #pragma unroll
            for (int a = 0; a < 2; a++) {
                const char* base = la + (wrow + a * 16 + m) * 256;
                int pc = ((4 * s + q) ^ m) * 16;     // cos physical chunk
                fac[a] = *(const bf16x8*)(base + pc);
                fas[a] = *(const bf16x8*)(base + (pc ^ 128)); // sin = cos ^ bit3
            }
            #pragma unroll
            for (int c = 0; c < 2; c++) {
                const char* base = lbp + (wcol + c * 16 + m) * 256;
                int pc = ((4 * s + q) ^ m) * 16;
                fbc[c] = *(const bf16x8*)(base + pc);
                fbs[c] = *(const bf16x8*)(base + (pc ^ 128));
            }
            #pragma unroll
            for (int a = 0; a < 2; a++)
                #pragma unroll
                for (int c = 0; c < 2; c++) {
                    accR[a][c]  = __builtin_amdgcn_mfma_f32_16x16x32_bf16(fac[a], fbc[c], accR[a][c], 0, 0, 0);
                    accR[a][c]  = __builtin_amdgcn_mfma_f32_16x16x32_bf16(fas[a], fbs[c], accR[a][c], 0, 0, 0);
                    accSC[a][c] = __builtin_amdgcn_mfma_f32_16x16x32_bf16(fas[a], fbc[c], accSC[a][c], 0, 0, 0);
                    accCS[a][c] = __builtin_amdgcn_mfma_f32_16x16x32_bf16(fac[a], fbs[c], accCS[a][c], 0, 0, 0);
                }
        }
    }

    // epilogue: deterministic slab stores, interleaved (re, im) float2
    float* sl = slabs + (size_t)h * ((size_t)NRED * 2)
                      + (size_t)(y * NPOS + pos) * 8192;
    #pragma unroll
    for (int a = 0; a < 2; a++)
        #pragma unroll
        for (int c = 0; c < 2; c++) {
            int ii = wrow + a * 16 + q * 4;      // C/D: row=(lane>>4)*4+reg
            int jj = wcol + c * 16 + m;          // C/D: col=lane&15
            #pragma unroll
            for (int r = 0; r < 4; r++) {
                int idx = (ii + r) * 64 + jj;
                float2 v = make_float2(accR[a][c][r], accSC[a][c][r] - accCS[a][c][r]);
                *(float2*)(sl + (size_t)idx * 2) = v;
            }
        }
}

// ---------------------------------------------------------------------------
// Kernel B2: per-tile blocks; sum 4 K-split slabs -> pci -> LDS [64][65] ->
// BOTH loss passes with fully-coalesced tgt reads. (UNCHANGED this round.)
// ---------------------------------------------------------------------------
__global__ void __launch_bounds__(256)
coh_kernel(const float* __restrict__ slabs, const float* __restrict__ tgt,
           float* __restrict__ accum)
{
    __shared__ float pl[64 * 65];            // padded 64x64 pci tile
    __shared__ float sred[4];
    const int blk = blockIdx.x;              // 0..319
    const int y   = blk / NPOS;
    const int pos = blk % NPOS;
    const int t   = threadIdx.x;
    const bool off = (pos >= 4);
    const float invf = 1.0f / (float)F_;
    const int ib = TI_[pos] * 64, jb = TJ_[pos] * 64;
    const float* ty = tgt + (size_t)y * (C_ * C_);
    const size_t sb0 = (size_t)(y * NPOS + pos) * 8192;

    float coh = 0.f;
    // elem pairs e = 2t + k*512 (8 chunks x 2 elems = 16 elems/thread)
    #pragma unroll
    for (int k = 0; k < 8; ++k) {
        int e = 2 * t + k * 512;
        float r0 = 0.f, s0 = 0.f, r1 = 0.f, s1 = 0.f;
        #pragma unroll
        for (int hh = 0; hh < 4; ++hh) {
            float4 v = *(const float4*)(slabs
                + (size_t)hh * ((size_t)NRED * 2) + sb0 + (size_t)e * 2);
            r0 += v.x; s0 += v.y; r1 += v.z; s1 += v.w;
        }
        float re0 = r0 * invf, im0 = s0 * invf;
        float re1 = r1 * invf, im1 = s1 * invf;
        float p0 = sqrtf(re0 * re0 + im0 * im0 + EPS_);
        float p1 = sqrtf(re1 * re1 + im1 * im1 + EPS_);
        int ii = e >> 6, jj = e & 63;
        pl[ii * 65 + jj]     = p0;
        pl[ii * 65 + jj + 1] = p1;
        // pass 1: tile (ib+ii, jb+jj..+1), coalesced float2 target read
        float2 tg = *(const float2*)(ty + (size_t)(ib + ii) * C_ + jb + jj);
        float d0 = p0 - tg.x, d1 = p1 - tg.y;
        coh += d0 * d0 + d1 * d1;
    }
    __syncthreads();

    if (off) {
        // pass 2: mirror tile rows jb+ii, cols ib+jj..+1; p^T from LDS
        #pragma unroll
        for (int k = 0; k < 8; ++k) {
            int e = 2 * t + k * 512;
            int ii = e >> 6, jj = e & 63;    // (row ii, col jj) of mirror tile
            float p0 = pl[jj * 65 + ii];         // p[jj][ii]
            float p1 = pl[(jj + 1) * 65 + ii];
            float2 tg = *(const float2*)(ty + (size_t)(jb + ii) * C_ + ib + jj);
            float d0 = p0 - tg.x, d1 = p1 - tg.y;
            coh += d0 * d0 + d1 * d1;
        }
    }

    #pragma unroll
    for (int o = 32; o > 0; o >>= 1) coh += __shfl_down(coh, o, 64);
    int lane = t & 63, w = t >> 6;
    if (lane == 0) sred[w] = coh;
    __syncthreads();
    if (t == 0)
        atomicAdd(&accum[2], sred[0] + sred[1] + sred[2] + sred[3]);
}

// ---------------------------------------------------------------------------
// Kernel C: finalize — sum the 64+64 ew partial slots + coh scalar
// ---------------------------------------------------------------------------
__global__ void fin_kernel(const float* __restrict__ accum,
                           const float* __restrict__ part,
                           float* __restrict__ out)
{
    int t = threadIdx.x;                     // 64 threads
    float m = part[t], p = part[64 + t];
    #pragma unroll
    for (int o = 32; o > 0; o >>= 1) {
        m += __shfl_down(m, o, 64);
        p += __shfl_down(p, o, 64);
    }
    if (t == 0) {
        float mag = m * (1.0f / (float)NTOT);
        float phs = p * (1.0f / (float)NTOT);
        float coh = accum[2] * (1.0f / (float)NCC);
        out[0] = ALPHA_ * mag + BETA_ * phs + GAMMA_ * coh;
        out[1] = mag;
        out[2] = phs;
        out[3] = coh;
    }
}

extern "C" void kernel_launch(void* const* d_in, const int* in_sizes, int n_in,
                              void* d_out, int out_size, void* d_ws, size_t ws_size,
                              hipStream_t stream)
{
    const float* mh  = (const float*)d_in[0];
    const float* ph  = (const float*)d_in[1];
    const float* mt  = (const float*)d_in[2];
    const float* pt  = (const float*)d_in[3];
    const float* tgt = (const float*)d_in[4];
    float* out = (float*)d_out;

    // ws layout: accum[0..3] @0 | part[128] @256 B | slabs @1024 B (41.9 MB)
    float* accum = (float*)d_ws;
    float* part  = (float*)((char*)d_ws + 256);
    float* slabs = (float*)((char*)d_ws + 1024);

    hipMemsetAsync(d_ws, 0, 1024, stream);   // scalars + partial slots

    ew_kernel<<<16384, 256, 0, stream>>>(
        (const float4*)mh, (const float4*)ph, (const float4*)mt, (const float4*)pt,
        part);

    pci_kernel<<<NBLK, 256, 0, stream>>>(ph, slabs);

    coh_kernel<<<320, 256, 0, stream>>>(slabs, tgt, accum);

    fin_kernel<<<1, 64, 0, stream>>>(accum, part, out);
}

// Round 6
// 287.576 us; speedup vs baseline: 1.0940x; 1.0940x over previous
//
#include <hip/hip_runtime.h>
#include <hip/hip_bf16.h>

#define ALPHA_ 1.0f
#define BETA_  0.5f
#define GAMMA_ 0.3f
#define EPS_   1e-8f

typedef unsigned short u16;
typedef unsigned int u32;

constexpr int B_ = 32, C_ = 256, F_ = 2048;
constexpr int NTOT = B_ * C_ * F_;          // 16777216
constexpr int NCC  = B_ * C_ * C_;          // 2097152
constexpr int NPOS = 10;                    // ti<=tj positions in 4x4 tile grid
constexpr int KSPL = 4;                     // K-split factor (K=2048 -> 4x512)
constexpr int NBLK = B_ * NPOS * KSPL;      // 1280 pci blocks (1280 % 8 == 0)
constexpr int NRED = B_ * NPOS * 64 * 64;   // 1310720 partial re/im elements

// symmetric tile positions: 4 diagonal first, then 6 strict-upper
__constant__ int TI_[NPOS] = {0, 1, 2, 3, 0, 0, 0, 1, 1, 2};
__constant__ int TJ_[NPOS] = {0, 1, 2, 3, 1, 2, 3, 2, 3, 3};

typedef __bf16 bf16x8 __attribute__((ext_vector_type(8)));
typedef float  f32x4  __attribute__((ext_vector_type(4)));

// round-to-nearest-even float -> bf16 bits (sin/cos inputs, no NaN/Inf)
__device__ __forceinline__ u32 f2bf(float x) {
    unsigned u = __float_as_uint(x);
    u += 0x7fffu + ((u >> 16) & 1u);
    return (u >> 16);
}

// ---------------------------------------------------------------------------
// Kernel A: magnitude loss ONLY (reads mh, mt = 128 MB).
// Read-only effective BW pins at ~2.4-2.8 TB/s across 4 structurally
// different schedules (R0-R5) => near the read-direction platform rate
// (copy 6.29 TB/s = ~3.15 each way). So: use the R4-proven access shape
// (2x float4 per array per thread) and stop fighting the schedule.
// Phase loss moved INTO pci's diagonal staging (kills 128 MB of reads).
// Splitting ew also guarantees pci/coh surface in the top-5 profile.
// ---------------------------------------------------------------------------
__global__ void __launch_bounds__(256)
mag_kernel(const float4* __restrict__ mh, const float4* __restrict__ mt,
           float* __restrict__ part)
{
    __shared__ float sm[4];
    const int g = blockIdx.x * 256 + threadIdx.x;   // 0..2097151
    float4 a0 = mh[2*g], a1 = mh[2*g+1];
    float4 b0 = mt[2*g], b1 = mt[2*g+1];

    float msum = 0.f, dm;
    dm = a0.x - b0.x; msum += dm * dm;
    dm = a0.y - b0.y; msum += dm * dm;
    dm = a0.z - b0.z; msum += dm * dm;
    dm = a0.w - b0.w; msum += dm * dm;
    dm = a1.x - b1.x; msum += dm * dm;
    dm = a1.y - b1.y; msum += dm * dm;
    dm = a1.z - b1.z; msum += dm * dm;
    dm = a1.w - b1.w; msum += dm * dm;

    #pragma unroll
    for (int o = 32; o > 0; o >>= 1) msum += __shfl_down(msum, o, 64);
    int lane = threadIdx.x & 63, wv = threadIdx.x >> 6;
    if (lane == 0) sm[wv] = msum;
    __syncthreads();
    if (threadIdx.x == 0)
        atomicAdd(&part[blockIdx.x & 63], sm[0] + sm[1] + sm[2] + sm[3]);
}

// ---------------------------------------------------------------------------
// Kernel B: batched MFMA partial re/im, SYMMETRIC tile set, K-split 4,
// with TWO additions this round:
//  (a) phase loss fused into diagonal-block staging: diag blocks
//      (pos 0..3, h 0..3) stage each (row,k) of ph exactly ONCE overall,
//      so they also load the matching pt elements and accumulate
//      1-cos(ph-pt) -> part[64+slot]. Removes the standalone 128 MB pass.
//  (b) register prefetch of next-iter panels issued at the TOP of the MFMA
//      phase: the compiler's vmcnt(0) drain at the next __syncthreads then
//      arrives after a full MFMA phase of latency hiding (T14 adapted).
// Staging layout / fragment reads / MFMA core byte-identical to verified.
// ---------------------------------------------------------------------------
__device__ __forceinline__ void stage8(float4 a, float4 b, char* base, int pc) {
    float v[8] = {a.x, a.y, a.z, a.w, b.x, b.y, b.z, b.w};
    u32 cu[8], su[8];
    #pragma unroll
    for (int j = 0; j < 8; j++) {
        float s, c;
        __sincosf(v[j], &s, &c);
        cu[j] = f2bf(c);
        su[j] = f2bf(s);
    }
    *(int4*)(base + pc) = make_int4(
        (int)(cu[0] | (cu[1] << 16)), (int)(cu[2] | (cu[3] << 16)),
        (int)(cu[4] | (cu[5] << 16)), (int)(cu[6] | (cu[7] << 16)));
    *(int4*)(base + (pc ^ 128)) = make_int4(
        (int)(su[0] | (su[1] << 16)), (int)(su[2] | (su[3] << 16)),
        (int)(su[4] | (su[5] << 16)), (int)(su[6] | (su[7] << 16)));
}

__device__ __forceinline__ float phs8(float4 a, float4 b, float4 qa, float4 qb) {
    float s = 0.f;
    s += 1.f - __cosf(a.x - qa.x);
    s += 1.f - __cosf(a.y - qa.y);
    s += 1.f - __cosf(a.z - qa.z);
    s += 1.f - __cosf(a.w - qa.w);
    s += 1.f - __cosf(b.x - qb.x);
    s += 1.f - __cosf(b.y - qb.y);
    s += 1.f - __cosf(b.z - qb.z);
    s += 1.f - __cosf(b.w - qb.w);
    return s;
}

__global__ void __launch_bounds__(256)
pci_kernel(const float* __restrict__ ph, const float* __restrict__ pt,
           float* __restrict__ slabs, float* __restrict__ part)
{
    __shared__ char lds[32768];          // A tile 16 KB | B tile 16 KB
    __shared__ float sred[4];
    char* la = lds;
    char* lb = lds + 16384;

    // bijective XCD swizzle (NBLK % 8 == 0)
    const int bid = blockIdx.x;
    const int l   = (bid & 7) * (NBLK / 8) + (bid >> 3);
    const int h   = l & 3;                   // K-split index 0..3
    const int t4  = l >> 2;
    const int pos = t4 % NPOS;               // symmetric tile position
    const int y   = t4 / NPOS;               // batch
    const int i0 = TI_[pos] * 64, j0 = TJ_[pos] * 64;
    const bool diag = (i0 == j0);
    char* lbp = diag ? la : lb;              // diagonal: B-fragments from la

    const int t    = threadIdx.x;
    const int lane = t & 63, w = t >> 6;
    const int wrow = (w >> 1) * 32, wcol = (w & 1) * 32;
    const int m = lane & 15, q = lane >> 4;

    // staging: thread t covers (row0, oct) and (row1=row0+32, oct);
    // oct covers k = h*512 + it*64 + oct*8 .. +7
    const int row0 = t >> 3, oct = t & 7;
    const int row1 = row0 + 32;
    const size_t offA0 = (size_t)(y * 256 + i0 + row0) * 2048 + h * 512 + oct * 8;
    const size_t offA1 = (size_t)(y * 256 + i0 + row1) * 2048 + h * 512 + oct * 8;
    const float* gA0 = ph + offA0;
    const float* gA1 = ph + offA1;
    const float* gB0 = ph + ((size_t)(y * 256 + j0 + row0) * 2048 + h * 512 + oct * 8);
    const float* gB1 = ph + ((size_t)(y * 256 + j0 + row1) * 2048 + h * 512 + oct * 8);
    const float* gQ0 = pt + offA0;           // pt mirror of A panel (diag only)
    const float* gQ1 = pt + offA1;
    char* dA0 = la + row0 * 256;  const int pc0 = (oct ^ (row0 & 15)) * 16;
    char* dA1 = la + row1 * 256;  const int pc1 = (oct ^ (row1 & 15)) * 16;
    char* dB0 = lb + row0 * 256;
    char* dB1 = lb + row1 * 256;

    f32x4 zero = {0.f, 0.f, 0.f, 0.f};
    f32x4 accR[2][2], accSC[2][2], accCS[2][2];
    #pragma unroll
    for (int a = 0; a < 2; a++)
        #pragma unroll
        for (int c = 0; c < 2; c++) {
            accR[a][c] = zero; accSC[a][c] = zero; accCS[a][c] = zero;
        }

    float psum = 0.f;
    // prologue: load it=0 panels into regs
    float4 a0 = *(const float4*)gA0, a1 = *(const float4*)(gA0 + 4);
    float4 a2 = *(const float4*)gA1, a3 = *(const float4*)(gA1 + 4);
    float4 b0, b1, b2, b3, q0, q1, q2, q3;
    if (diag) {
        q0 = *(const float4*)gQ0; q1 = *(const float4*)(gQ0 + 4);
        q2 = *(const float4*)gQ1; q3 = *(const float4*)(gQ1 + 4);
    } else {
        b0 = *(const float4*)gB0; b1 = *(const float4*)(gB0 + 4);
        b2 = *(const float4*)gB1; b3 = *(const float4*)(gB1 + 4);
    }
    gA0 += 64; gA1 += 64; gB0 += 64; gB1 += 64; gQ0 += 64; gQ1 += 64;

    for (int it = 0; it < 8; ++it) {         // 8 iters x BK=64 = K/4
        __syncthreads();                     // prev MFMA done; prefetch drained
        stage8(a0, a1, dA0, pc0);
        stage8(a2, a3, dA1, pc1);
        if (diag) {
            psum += phs8(a0, a1, q0, q1);
            psum += phs8(a2, a3, q2, q3);
        } else {
            stage8(b0, b1, dB0, pc0);
            stage8(b2, b3, dB1, pc1);
        }
        __syncthreads();                     // ds_writes visible to all waves

        if (it < 7) {                        // prefetch next iter's panels;
            a0 = *(const float4*)gA0; a1 = *(const float4*)(gA0 + 4);
            a2 = *(const float4*)gA1; a3 = *(const float4*)(gA1 + 4);
            if (diag) {
                q0 = *(const float4*)gQ0; q1 = *(const float4*)(gQ0 + 4);
                q2 = *(const float4*)gQ1; q3 = *(const float4*)(gQ1 + 4);
            } else {
                b0 = *(const float4*)gB0; b1 = *(const float4*)(gB0 + 4);
                b2 = *(const float4*)gB1; b3 = *(const float4*)(gB1 + 4);
            }
            gA0 += 64; gA1 += 64; gB0 += 64; gB1 += 64; gQ0 += 64; gQ1 += 64;
            __builtin_amdgcn_sched_barrier(0);   // keep issue above MFMA phase
        }

        #pragma unroll
        for (int s = 0; s < 2; ++s) {
            bf16x8 fac[2], fas[2], fbc[2], fbs[2];
            #pragma unroll
            for (int a = 0; a < 2; a++) {
                const char* base = la + (wrow + a * 16 + m) * 256;
                int pc = ((4 * s + q) ^ m) * 16;     // cos physical chunk
                fac[a] = *(const bf16x8*)(base + pc);
                fas[a] = *(const bf16x8*)(base + (pc ^ 128)); // sin = cos ^ bit3
            }
            #pragma unroll
            for (int c = 0; c < 2; c++) {
                const char* base = lbp + (wcol + c * 16 + m) * 256;
                int pc = ((4 * s + q) ^ m) * 16;
                fbc[c] = *(const bf16x8*)(base + pc);
                fbs[c] = *(const bf16x8*)(base + (pc ^ 128));
            }
            #pragma unroll
            for (int a = 0; a < 2; a++)
                #pragma unroll
                for (int c = 0; c < 2; c++) {
                    accR[a][c]  = __builtin_amdgcn_mfma_f32_16x16x32_bf16(fac[a], fbc[c], accR[a][c], 0, 0, 0);
                    accR[a][c]  = __builtin_amdgcn_mfma_f32_16x16x32_bf16(fas[a], fbs[c], accR[a][c], 0, 0, 0);
                    accSC[a][c] = __builtin_amdgcn_mfma_f32_16x16x32_bf16(fas[a], fbc[c], accSC[a][c], 0, 0, 0);
                    accCS[a][c] = __builtin_amdgcn_mfma_f32_16x16x32_bf16(fac[a], fbs[c], accCS[a][c], 0, 0, 0);
                }
        }
    }

    // epilogue 1: deterministic slab stores, interleaved (re, im) float2
    float* sl = slabs + (size_t)h * ((size_t)NRED * 2)
                      + (size_t)(y * NPOS + pos) * 8192;
    #pragma unroll
    for (int a = 0; a < 2; a++)
        #pragma unroll
        for (int c = 0; c < 2; c++) {
            int ii = wrow + a * 16 + q * 4;      // C/D: row=(lane>>4)*4+reg
            int jj = wcol + c * 16 + m;          // C/D: col=lane&15
            #pragma unroll
            for (int r = 0; r < 4; r++) {
                int idx = (ii + r) * 64 + jj;
                float2 v = make_float2(accR[a][c][r], accSC[a][c][r] - accCS[a][c][r]);
                *(float2*)(sl + (size_t)idx * 2) = v;
            }
        }

    // epilogue 2: phase-loss block reduction (diag blocks only; each ph
    // element was staged exactly once across the 512 diag blocks)
    if (diag) {
        #pragma unroll
        for (int o = 32; o > 0; o >>= 1) psum += __shfl_down(psum, o, 64);
        if (lane == 0) sred[w] = psum;
        __syncthreads();
        if (t == 0)
            atomicAdd(&part[64 + (bid & 63)], sred[0] + sred[1] + sred[2] + sred[3]);
    }
}

// ---------------------------------------------------------------------------
// Kernel B2: per-tile blocks; sum 4 K-split slabs -> pci -> LDS [64][65] ->
// BOTH loss passes with fully-coalesced tgt reads. (UNCHANGED; will be
// measured in next round's top-5.)
// ---------------------------------------------------------------------------
__global__ void __launch_bounds__(256)
coh_kernel(const float* __restrict__ slabs, const float* __restrict__ tgt,
           float* __restrict__ accum)
{
    __shared__ float pl[64 * 65];            // padded 64x64 pci tile
    __shared__ float sred[4];
    const int blk = blockIdx.x;              // 0..319
    const int y   = blk / NPOS;
    const int pos = blk % NPOS;
    const int t   = threadIdx.x;
    const bool off = (pos >= 4);
    const float invf = 1.0f / (float)F_;
    const int ib = TI_[pos] * 64, jb = TJ_[pos] * 64;
    const float* ty = tgt + (size_t)y * (C_ * C_);
    const size_t sb0 = (size_t)(y * NPOS + pos) * 8192;

    float coh = 0.f;
    // elem pairs e = 2t + k*512 (8 chunks x 2 elems = 16 elems/thread)
    #pragma unroll
    for (int k = 0; k < 8; ++k) {
        int e = 2 * t + k * 512;
        float r0 = 0.f, s0 = 0.f, r1 = 0.f, s1 = 0.f;
        #pragma unroll
        for (int hh = 0; hh < 4; ++hh) {
            float4 v = *(const float4*)(slabs
                + (size_t)hh * ((size_t)NRED * 2) + sb0 + (size_t)e * 2);
            r0 += v.x; s0 += v.y; r1 += v.z; s1 += v.w;
        }
        float re0 = r0 * invf, im0 = s0 * invf;
        float re1 = r1 * invf, im1 = s1 * invf;
        float p0 = sqrtf(re0 * re0 + im0 * im0 + EPS_);
        float p1 = sqrtf(re1 * re1 + im1 * im1 + EPS_);
        int ii = e >> 6, jj = e & 63;
        pl[ii * 65 + jj]     = p0;
        pl[ii * 65 + jj + 1] = p1;
        // pass 1: tile (ib+ii, jb+jj..+1), coalesced float2 target read
        float2 tg = *(const float2*)(ty + (size_t)(ib + ii) * C_ + jb + jj);
        float d0 = p0 - tg.x, d1 = p1 - tg.y;
        coh += d0 * d0 + d1 * d1;
    }
    __syncthreads();

    if (off) {
        // pass 2: mirror tile rows jb+ii, cols ib+jj..+1; p^T from LDS
        #pragma unroll
        for (int k = 0; k < 8; ++k) {
            int e = 2 * t + k * 512;
            int ii = e >> 6, jj = e & 63;    // (row ii, col jj) of mirror tile
            float p0 = pl[jj * 65 + ii];         // p[jj][ii]
            float p1 = pl[(jj + 1) * 65 + ii];
            float2 tg = *(const float2*)(ty + (size_t)(jb + ii) * C_ + ib + jj);
            float d0 = p0 - tg.x, d1 = p1 - tg.y;
            coh += d0 * d0 + d1 * d1;
        }
    }

    #pragma unroll
    for (int o = 32; o > 0; o >>= 1) coh += __shfl_down(coh, o, 64);
    int lane = t & 63, w = t >> 6;
    if (lane == 0) sred[w] = coh;
    __syncthreads();
    if (t == 0)
        atomicAdd(&accum[2], sred[0] + sred[1] + sred[2] + sred[3]);
}

// ---------------------------------------------------------------------------
// Kernel C: finalize — sum the 64 mag + 64 phs partial slots + coh scalar
// ---------------------------------------------------------------------------
__global__ void fin_kernel(const float* __restrict__ accum,
                           const float* __restrict__ part,
                           float* __restrict__ out)
{
    int t = threadIdx.x;                     // 64 threads
    float m = part[t], p = part[64 + t];
    #pragma unroll
    for (int o = 32; o > 0; o >>= 1) {
        m += __shfl_down(m, o, 64);
        p += __shfl_down(p, o, 64);
    }
    if (t == 0) {
        float mag = m * (1.0f / (float)NTOT);
        float phs = p * (1.0f / (float)NTOT);
        float coh = accum[2] * (1.0f / (float)NCC);
        out[0] = ALPHA_ * mag + BETA_ * phs + GAMMA_ * coh;
        out[1] = mag;
        out[2] = phs;
        out[3] = coh;
    }
}

extern "C" void kernel_launch(void* const* d_in, const int* in_sizes, int n_in,
                              void* d_out, int out_size, void* d_ws, size_t ws_size,
                              hipStream_t stream)
{
    const float* mh  = (const float*)d_in[0];
    const float* ph  = (const float*)d_in[1];
    const float* mt  = (const float*)d_in[2];
    const float* pt  = (const float*)d_in[3];
    const float* tgt = (const float*)d_in[4];
    float* out = (float*)d_out;

    // ws layout: accum[0..3] @0 | part[128] @256 B | slabs @1024 B (41.9 MB)
    float* accum = (float*)d_ws;
    float* part  = (float*)((char*)d_ws + 256);
    float* slabs = (float*)((char*)d_ws + 1024);

    hipMemsetAsync(d_ws, 0, 1024, stream);   // scalars + partial slots

    mag_kernel<<<8192, 256, 0, stream>>>(
        (const float4*)mh, (const float4*)mt, part);

    pci_kernel<<<NBLK, 256, 0, stream>>>(ph, pt, slabs, part);

    coh_kernel<<<320, 256, 0, stream>>>(slabs, tgt, accum);

    fin_kernel<<<1, 64, 0, stream>>>(accum, part, out);
}

// Round 7
// 272.034 us; speedup vs baseline: 1.1565x; 1.0571x over previous
//
#include <hip/hip_runtime.h>
#include <hip/hip_bf16.h>

#define ALPHA_ 1.0f
#define BETA_  0.5f
#define GAMMA_ 0.3f
#define EPS_   1e-8f

typedef unsigned short u16;
typedef unsigned int u32;

constexpr int B_ = 32, C_ = 256, F_ = 2048;
constexpr int NTOT = B_ * C_ * F_;          // 16777216
constexpr int NCC  = B_ * C_ * C_;          // 2097152
constexpr int NPOS = 10;                    // ti<=tj positions in 4x4 tile grid
constexpr int KSPL = 4;                     // K-split factor (K=2048 -> 4x512)
constexpr int NBLK = B_ * NPOS * KSPL;      // 1280 pci blocks (1280 % 8 == 0)
constexpr int NMAG = 8192;                  // mag blocks appended to the grid
constexpr int NRED = B_ * NPOS * 64 * 64;   // 1310720 partial re/im elements

// symmetric tile positions: 4 diagonal first, then 6 strict-upper
__constant__ int TI_[NPOS] = {0, 1, 2, 3, 0, 0, 0, 1, 1, 2};
__constant__ int TJ_[NPOS] = {0, 1, 2, 3, 1, 2, 3, 2, 3, 3};

typedef __bf16 bf16x8 __attribute__((ext_vector_type(8)));
typedef float  f32x4  __attribute__((ext_vector_type(4)));

// ---------------------------------------------------------------------------
// stage8: 8 phases -> sincos -> bf16 (RTNE via hardware v_cvt_pk_bf16_f32,
// same rounding as the previous manual bit-RNE but ~1/5 the pack VALU ops)
// -> swizzled 16B LDS stores (cos chunk at pc, sin at pc^128).
// ---------------------------------------------------------------------------
__device__ __forceinline__ void stage8(float4 a, float4 b, char* base, int pc) {
    float v[8] = {a.x, a.y, a.z, a.w, b.x, b.y, b.z, b.w};
    bf16x8 vc, vs;
    #pragma unroll
    for (int j = 0; j < 8; j++) {
        float s, c;
        __sincosf(v[j], &s, &c);
        vc[j] = (__bf16)c;
        vs[j] = (__bf16)s;
    }
    *(bf16x8*)(base + pc) = vc;
    *(bf16x8*)(base + (pc ^ 128)) = vs;
}

__device__ __forceinline__ float phs8(float4 a, float4 b, float4 qa, float4 qb) {
    float s = 0.f;
    s += 1.f - __cosf(a.x - qa.x);
    s += 1.f - __cosf(a.y - qa.y);
    s += 1.f - __cosf(a.z - qa.z);
    s += 1.f - __cosf(a.w - qa.w);
    s += 1.f - __cosf(b.x - qb.x);
    s += 1.f - __cosf(b.y - qb.y);
    s += 1.f - __cosf(b.z - qb.z);
    s += 1.f - __cosf(b.w - qb.w);
    return s;
}

// ---------------------------------------------------------------------------
// FUSED kernel: heterogeneous blocks.
//   bid <  NBLK : pci block (byte-identical R6 inner loop: MFMA partial
//                 re/im, symmetric tile set, K-split 4, phase loss fused
//                 into diagonal staging, reg prefetch across MFMA phase).
//   bid >= NBLK : mag block (pure 128 MB streamer, R6-verified shape).
// R6 diagnosis: pci is latency/barrier-bound — no pipe >35% busy, ~20 us
// per block of which ~15 us is stall. mag is a pure VMEM streamer. Mixing
// them on each CU lets mag's loads fill pci's barrier stalls, targeting
// max(mem, pci-path) instead of the sum; also one fewer dispatch gap.
// pci blocks occupy the low blockIdx range so they dispatch first.
// ---------------------------------------------------------------------------
__global__ void __launch_bounds__(256)
fused_kernel(const float* __restrict__ ph, const float* __restrict__ pt,
             const float4* __restrict__ mh, const float4* __restrict__ mt,
             float* __restrict__ slabs, float* __restrict__ part)
{
    __shared__ char lds[32768];          // pci: A tile 16 KB | B tile 16 KB
    __shared__ float sred[4];
    const int bid = blockIdx.x;
    const int t    = threadIdx.x;
    const int lane = t & 63, w = t >> 6;

    if (bid >= NBLK) {
        // ------------------------- mag path -------------------------------
        const int g = (bid - NBLK) * 256 + t;       // 0..2097151
        float4 a0 = mh[2*g], a1 = mh[2*g+1];
        float4 b0 = mt[2*g], b1 = mt[2*g+1];
        float msum = 0.f, dm;
        dm = a0.x - b0.x; msum += dm * dm;
        dm = a0.y - b0.y; msum += dm * dm;
        dm = a0.z - b0.z; msum += dm * dm;
        dm = a0.w - b0.w; msum += dm * dm;
        dm = a1.x - b1.x; msum += dm * dm;
        dm = a1.y - b1.y; msum += dm * dm;
        dm = a1.z - b1.z; msum += dm * dm;
        dm = a1.w - b1.w; msum += dm * dm;
        #pragma unroll
        for (int o = 32; o > 0; o >>= 1) msum += __shfl_down(msum, o, 64);
        if (lane == 0) sred[w] = msum;
        __syncthreads();
        if (t == 0)
            atomicAdd(&part[bid & 63], sred[0] + sred[1] + sred[2] + sred[3]);
        return;
    }

    // --------------------------- pci path ---------------------------------
    char* la = lds;
    char* lb = lds + 16384;

    // bijective XCD swizzle (NBLK % 8 == 0)
    const int l   = (bid & 7) * (NBLK / 8) + (bid >> 3);
    const int h   = l & 3;                   // K-split index 0..3
    const int t4  = l >> 2;
    const int pos = t4 % NPOS;               // symmetric tile position
    const int y   = t4 / NPOS;               // batch
    const int i0 = TI_[pos] * 64, j0 = TJ_[pos] * 64;
    const bool diag = (i0 == j0);
    char* lbp = diag ? la : lb;              // diagonal: B-fragments from la

    const int wrow = (w >> 1) * 32, wcol = (w & 1) * 32;
    const int m = lane & 15, q = lane >> 4;

    // staging: thread t covers (row0, oct) and (row1=row0+32, oct);
    // oct covers k = h*512 + it*64 + oct*8 .. +7
    const int row0 = t >> 3, oct = t & 7;
    const int row1 = row0 + 32;
    const size_t offA0 = (size_t)(y * 256 + i0 + row0) * 2048 + h * 512 + oct * 8;
    const size_t offA1 = (size_t)(y * 256 + i0 + row1) * 2048 + h * 512 + oct * 8;
    const float* gA0 = ph + offA0;
    const float* gA1 = ph + offA1;
    const float* gB0 = ph + ((size_t)(y * 256 + j0 + row0) * 2048 + h * 512 + oct * 8);
    const float* gB1 = ph + ((size_t)(y * 256 + j0 + row1) * 2048 + h * 512 + oct * 8);
    const float* gQ0 = pt + offA0;           // pt mirror of A panel (diag only)
    const float* gQ1 = pt + offA1;
    char* dA0 = la + row0 * 256;  const int pc0 = (oct ^ (row0 & 15)) * 16;
    char* dA1 = la + row1 * 256;  const int pc1 = (oct ^ (row1 & 15)) * 16;
    char* dB0 = lb + row0 * 256;
    char* dB1 = lb + row1 * 256;

    f32x4 zero = {0.f, 0.f, 0.f, 0.f};
    f32x4 accR[2][2], accSC[2][2], accCS[2][2];
    #pragma unroll
    for (int a = 0; a < 2; a++)
        #pragma unroll
        for (int c = 0; c < 2; c++) {
            accR[a][c] = zero; accSC[a][c] = zero; accCS[a][c] = zero;
        }

    float psum = 0.f;
    // prologue: load it=0 panels into regs
    float4 a0 = *(const float4*)gA0, a1 = *(const float4*)(gA0 + 4);
    float4 a2 = *(const float4*)gA1, a3 = *(const float4*)(gA1 + 4);
    float4 b0, b1, b2, b3, q0, q1, q2, q3;
    if (diag) {
        q0 = *(const float4*)gQ0; q1 = *(const float4*)(gQ0 + 4);
        q2 = *(const float4*)gQ1; q3 = *(const float4*)(gQ1 + 4);
    } else {
        b0 = *(const float4*)gB0; b1 = *(const float4*)(gB0 + 4);
        b2 = *(const float4*)gB1; b3 = *(const float4*)(gB1 + 4);
    }
    gA0 += 64; gA1 += 64; gB0 += 64; gB1 += 64; gQ0 += 64; gQ1 += 64;

    for (int it = 0; it < 8; ++it) {         // 8 iters x BK=64 = K/4
        __syncthreads();                     // prev MFMA done; prefetch drained
        stage8(a0, a1, dA0, pc0);
        stage8(a2, a3, dA1, pc1);
        if (diag) {
            psum += phs8(a0, a1, q0, q1);
            psum += phs8(a2, a3, q2, q3);
        } else {
            stage8(b0, b1, dB0, pc0);
            stage8(b2, b3, dB1, pc1);
        }
        __syncthreads();                     // ds_writes visible to all waves

        if (it < 7) {                        // prefetch next iter's panels;
            a0 = *(const float4*)gA0; a1 = *(const float4*)(gA0 + 4);
            a2 = *(const float4*)gA1; a3 = *(const float4*)(gA1 + 4);
            if (diag) {
                q0 = *(const float4*)gQ0; q1 = *(const float4*)(gQ0 + 4);
                q2 = *(const float4*)gQ1; q3 = *(const float4*)(gQ1 + 4);
            } else {
                b0 = *(const float4*)gB0; b1 = *(const float4*)(gB0 + 4);
                b2 = *(const float4*)gB1; b3 = *(const float4*)(gB1 + 4);
            }
            gA0 += 64; gA1 += 64; gB0 += 64; gB1 += 64; gQ0 += 64; gQ1 += 64;
            __builtin_amdgcn_sched_barrier(0);   // keep issue above MFMA phase
        }

        #pragma unroll
        for (int s = 0; s < 2; ++s) {
            bf16x8 fac[2], fas[2], fbc[2], fbs[2];
            #pragma unroll
            for (int a = 0; a < 2; a++) {
                const char* base = la + (wrow + a * 16 + m) * 256;
                int pc = ((4 * s + q) ^ m) * 16;     // cos physical chunk
                fac[a] = *(const bf16x8*)(base + pc);
                fas[a] = *(const bf16x8*)(base + (pc ^ 128)); // sin = cos ^ bit3
            }
            #pragma unroll
            for (int c = 0; c < 2; c++) {
                const char* base = lbp + (wcol + c * 16 + m) * 256;
                int pc = ((4 * s + q) ^ m) * 16;
                fbc[c] = *(const bf16x8*)(base + pc);
                fbs[c] = *(const bf16x8*)(base + (pc ^ 128));
            }
            #pragma unroll
            for (int a = 0; a < 2; a++)
                #pragma unroll
                for (int c = 0; c < 2; c++) {
                    accR[a][c]  = __builtin_amdgcn_mfma_f32_16x16x32_bf16(fac[a], fbc[c], accR[a][c], 0, 0, 0);
                    accR[a][c]  = __builtin_amdgcn_mfma_f32_16x16x32_bf16(fas[a], fbs[c], accR[a][c], 0, 0, 0);
                    accSC[a][c] = __builtin_amdgcn_mfma_f32_16x16x32_bf16(fas[a], fbc[c], accSC[a][c], 0, 0, 0);
                    accCS[a][c] = __builtin_amdgcn_mfma_f32_16x16x32_bf16(fac[a], fbs[c], accCS[a][c], 0, 0, 0);
                }
        }
    }

    // epilogue 1: deterministic slab stores, interleaved (re, im) float2
    float* sl = slabs + (size_t)h * ((size_t)NRED * 2)
                      + (size_t)(y * NPOS + pos) * 8192;
    #pragma unroll
    for (int a = 0; a < 2; a++)
        #pragma unroll
        for (int c = 0; c < 2; c++) {
            int ii = wrow + a * 16 + q * 4;      // C/D: row=(lane>>4)*4+reg
            int jj = wcol + c * 16 + m;          // C/D: col=lane&15
            #pragma unroll
            for (int r = 0; r < 4; r++) {
                int idx = (ii + r) * 64 + jj;
                float2 v = make_float2(accR[a][c][r], accSC[a][c][r] - accCS[a][c][r]);
                *(float2*)(sl + (size_t)idx * 2) = v;
            }
        }

    // epilogue 2: phase-loss block reduction (diag blocks only; each ph
    // element is staged exactly once across the 512 diag blocks)
    if (diag) {
        #pragma unroll
        for (int o = 32; o > 0; o >>= 1) psum += __shfl_down(psum, o, 64);
        if (lane == 0) sred[w] = psum;
        __syncthreads();
        if (t == 0)
            atomicAdd(&part[64 + (bid & 63)], sred[0] + sred[1] + sred[2] + sred[3]);
    }
}

// ---------------------------------------------------------------------------
// Kernel B2: per-tile blocks; sum 4 K-split slabs -> pci -> LDS [64][65] ->
// BOTH loss passes with fully-coalesced tgt reads. (UNCHANGED; surfaces in
// the top-5 this round for measurement.)
// ---------------------------------------------------------------------------
__global__ void __launch_bounds__(256)
coh_kernel(const float* __restrict__ slabs, const float* __restrict__ tgt,
           float* __restrict__ accum)
{
    __shared__ float pl[64 * 65];            // padded 64x64 pci tile
    __shared__ float sred[4];
    const int blk = blockIdx.x;              // 0..319
    const int y   = blk / NPOS;
    const int pos = blk % NPOS;
    const int t   = threadIdx.x;
    const bool off = (pos >= 4);
    const float invf = 1.0f / (float)F_;
    const int ib = TI_[pos] * 64, jb = TJ_[pos] * 64;
    const float* ty = tgt + (size_t)y * (C_ * C_);
    const size_t sb0 = (size_t)(y * NPOS + pos) * 8192;

    float coh = 0.f;
    // elem pairs e = 2t + k*512 (8 chunks x 2 elems = 16 elems/thread)
    #pragma unroll
    for (int k = 0; k < 8; ++k) {
        int e = 2 * t + k * 512;
        float r0 = 0.f, s0 = 0.f, r1 = 0.f, s1 = 0.f;
        #pragma unroll
        for (int hh = 0; hh < 4; ++hh) {
            float4 v = *(const float4*)(slabs
                + (size_t)hh * ((size_t)NRED * 2) + sb0 + (size_t)e * 2);
            r0 += v.x; s0 += v.y; r1 += v.z; s1 += v.w;
        }
        float re0 = r0 * invf, im0 = s0 * invf;
        float re1 = r1 * invf, im1 = s1 * invf;
        float p0 = sqrtf(re0 * re0 + im0 * im0 + EPS_);
        float p1 = sqrtf(re1 * re1 + im1 * im1 + EPS_);
        int ii = e >> 6, jj = e & 63;
        pl[ii * 65 + jj]     = p0;
        pl[ii * 65 + jj + 1] = p1;
        // pass 1: tile (ib+ii, jb+jj..+1), coalesced float2 target read
        float2 tg = *(const float2*)(ty + (size_t)(ib + ii) * C_ + jb + jj);
        float d0 = p0 - tg.x, d1 = p1 - tg.y;
        coh += d0 * d0 + d1 * d1;
    }
    __syncthreads();

    if (off) {
        // pass 2: mirror tile rows jb+ii, cols ib+jj..+1; p^T from LDS
        #pragma unroll
        for (int k = 0; k < 8; ++k) {
            int e = 2 * t + k * 512;
            int ii = e >> 6, jj = e & 63;    // (row ii, col jj) of mirror tile
            float p0 = pl[jj * 65 + ii];         // p[jj][ii]
            float p1 = pl[(jj + 1) * 65 + ii];
            float2 tg = *(const float2*)(ty + (size_t)(jb + ii) * C_ + ib + jj);
            float d0 = p0 - tg.x, d1 = p1 - tg.y;
            coh += d0 * d0 + d1 * d1;
        }
    }

    #pragma unroll
    for (int o = 32; o > 0; o >>= 1) coh += __shfl_down(coh, o, 64);
    int lane = t & 63, w = t >> 6;
    if (lane == 0) sred[w] = coh;
    __syncthreads();
    if (t == 0)
        atomicAdd(&accum[2], sred[0] + sred[1] + sred[2] + sred[3]);
}

// ---------------------------------------------------------------------------
// Kernel C: finalize — sum the 64 mag + 64 phs partial slots + coh scalar
// ---------------------------------------------------------------------------
__global__ void fin_kernel(const float* __restrict__ accum,
                           const float* __restrict__ part,
                           float* __restrict__ out)
{
    int t = threadIdx.x;                     // 64 threads
    float m = part[t], p = part[64 + t];
    #pragma unroll
    for (int o = 32; o > 0; o >>= 1) {
        m += __shfl_down(m, o, 64);
        p += __shfl_down(p, o, 64);
    }
    if (t == 0) {
        float mag = m * (1.0f / (float)NTOT);
        float phs = p * (1.0f / (float)NTOT);
        float coh = accum[2] * (1.0f / (float)NCC);
        out[0] = ALPHA_ * mag + BETA_ * phs + GAMMA_ * coh;
        out[1] = mag;
        out[2] = phs;
        out[3] = coh;
    }
}

extern "C" void kernel_launch(void* const* d_in, const int* in_sizes, int n_in,
                              void* d_out, int out_size, void* d_ws, size_t ws_size,
                              hipStream_t stream)
{
    const float* mh  = (const float*)d_in[0];
    const float* ph  = (const float*)d_in[1];
    const float* mt  = (const float*)d_in[2];
    const float* pt  = (const float*)d_in[3];
    const float* tgt = (const float*)d_in[4];
    float* out = (float*)d_out;

    // ws layout: accum[0..3] @0 | part[128] @256 B | slabs @1024 B (41.9 MB)
    float* accum = (float*)d_ws;
    float* part  = (float*)((char*)d_ws + 256);
    float* slabs = (float*)((char*)d_ws + 1024);

    hipMemsetAsync(d_ws, 0, 1024, stream);   // scalars + partial slots

    fused_kernel<<<NBLK + NMAG, 256, 0, stream>>>(
        ph, pt, (const float4*)mh, (const float4*)mt, slabs, part);

    coh_kernel<<<320, 256, 0, stream>>>(slabs, tgt, accum);

    fin_kernel<<<1, 64, 0, stream>>>(accum, part, out);
}